// Round 14
// baseline (236.987 us; speedup 1.0000x reference)
//
#include <hip/hip_runtime.h>
#include <stdint.h>

// Problem constants
#define NB       64
#define FIN      12
#define HD       64
#define NHEADS   4
#define DHEAD    16
#define NLAYERS  3
#define ODIM     128
#define LN_EPS   1e-5f
#define BTOT     8192

#define NTH      256   // 4 independent waves per block; ONE WAVE = ONE GRAPH
#define NWAVE    4
#define NW       (NLAYERS * 4)
#define WFRAG    4096  // u16 per packed weight
#define WIN_U16  2048  // packed W_in^T (zero-padded K=32)
#define NTILES   10    // band tiles (|tj-ti|<=1) of the 4x4 tile grid
#define MSK_U32  (NTILES * 64 * 2)   // 1280 u32 of f16 0/1 fragment masks
#define HROW     72    // u16 row stride of the per-wave h/O round-trip buffer

typedef unsigned int       u32;
typedef unsigned short     u16;
typedef unsigned long long u64;
typedef _Float16           f16;

typedef f16    f16x8 __attribute__((ext_vector_type(8)));
typedef f16    f16x4 __attribute__((ext_vector_type(4)));
typedef f16    h2    __attribute__((ext_vector_type(2)));
typedef __fp16 hh2   __attribute__((ext_vector_type(2)));
typedef float  f32x4 __attribute__((ext_vector_type(4)));
union U128h { uint4 u; f16x8 v8; f16x4 v4h[2]; h2 v2[4]; };
union U64h  { uint2 u; f16x4 v4; h2 h[2]; u32 w[2]; u16 s[4]; };

#if __has_builtin(__builtin_amdgcn_exp2f)
  __device__ __forceinline__ float e2(float x) { return __builtin_amdgcn_exp2f(x); }
#else
  __device__ __forceinline__ float e2(float x) { return exp2f(x); }
#endif

__device__ __forceinline__ float fdot2h(h2 a, h2 b, float c) {
#if __has_builtin(__builtin_amdgcn_fdot2)
  return __builtin_amdgcn_fdot2(a, b, c, false);
#else
  return c + (float)a[0] * (float)b[0] + (float)a[1] * (float)b[1];
#endif
}

#if __has_builtin(__builtin_amdgcn_cvt_pkrtz)
__device__ __forceinline__ u32 packh2(float a, float b) {
  hh2 p = __builtin_amdgcn_cvt_pkrtz(a, b);
  return *(u32*)&p;
}
#else
__device__ __forceinline__ u32 packh2(float a, float b) {
  h2 p = {(f16)a, (f16)b};
  return *(u32*)&p;
}
#endif

#if __has_builtin(__builtin_amdgcn_mfma_f32_16x16x16f16)
__device__ __forceinline__ f32x4 mfma16(f16x4 a, f16x4 b, f32x4 c) {
  return __builtin_amdgcn_mfma_f32_16x16x16f16(a, b, c, 0, 0, 0);
}
#elif __has_builtin(__builtin_amdgcn_mfma_f32_16x16x16_f16)
__device__ __forceinline__ f32x4 mfma16(f16x4 a, f16x4 b, f32x4 c) {
  return __builtin_amdgcn_mfma_f32_16x16x16_f16(a, b, c, 0, 0, 0);
}
#else
__device__ __forceinline__ f32x4 mfma16(f16x4 a, f16x4 b, f32x4 c) {
  f16x8 a8 = {a[0], a[1], a[2], a[3], (f16)0, (f16)0, (f16)0, (f16)0};
  f16x8 b8 = {b[0], b[1], b[2], b[3], (f16)0, (f16)0, (f16)0, (f16)0};
  return __builtin_amdgcn_mfma_f32_16x16x32_f16(a8, b8, c, 0, 0, 0);
}
#endif

__device__ __forceinline__ f32x4 mfma32(f16x8 a, f16x8 b, f32x4 c) {
  return __builtin_amdgcn_mfma_f32_16x16x32_f16(a, b, c, 0, 0, 0);
}

__device__ __forceinline__ f16x4 pa4(u32 w0, u32 w1) {
  U64h u; u.w[0] = w0; u.w[1] = w1; return u.v4;
}

// LDS: per-wave MLP scratch + per-wave h/O round-trip buffer + per-wave f32
// residual home for nodes 32..63 (r14: hr is [2][4] REGISTERS for nodes 0..31
// only; the other half's residual lives in LDS permanently, cutting 32 regs
// of cold liveness across V/QK/attention -- r13's spill trigger).
// 71680 B/block -> 2 blocks/CU (143 KB of the 160 KB pool).
struct __align__(16) Smem {
  float scr[NWAVE][128];         // 2048 B: pooled[64] + y1[64]
  u16   hob[NWAVE][64 * HROW];   // 36864 B: [wave][node][HROW] h then O
  float hrs[NWAVE][8][64][4];    // 32768 B: [wave][(ng-2)*4+mt][lane][4]
};  // 71680 B

// ---------------- prep: unchanged (verified 10 rounds).
extern "C" __global__ void __launch_bounds__(256)
prep_pack(const float* __restrict__ Wq, const float* __restrict__ Wk,
          const float* __restrict__ Wv, const float* __restrict__ Wo,
          const float* __restrict__ W_in, const int* __restrict__ adj,
          u16* __restrict__ wsW) {
  const int w = blockIdx.x;
  if (w < NW) {
    const int l = w >> 2, ty = w & 3;
    u16* dst = wsW + w * WFRAG;
    if (ty == 2) {
      const float* src = Wv + l * HD * HD;
      for (int f = threadIdx.x; f < 512; f += 256) {
        const int lane = f & 63, fi = f >> 6;
        const int dt = fi >> 1, c = fi & 1;
        const int mm = lane & 15, mq = (lane >> 4) & 3;
        u16 tmp[8];
        #pragma unroll
        for (int e = 0; e < 8; ++e) {
          const int kk = c * 2 + (e >> 2), j = e & 3;
          f16 hv = (f16)src[(kk * 16 + mq * 4 + j) * HD + dt * 16 + mm];
          tmp[e] = *(u16*)&hv;
        }
        *(uint4*)(dst + f * 8) = *(const uint4*)tmp;
      }
    } else {
      const float* src = (ty == 0 ? Wq : ty == 1 ? Wk : Wo) + l * HD * HD;
      const float sc = (ty == 0) ? (0.25f * 1.44269504f) : 1.0f;
      for (int f = threadIdx.x; f < 512; f += 256) {
        const int lane = f & 63, kh = (f >> 6) & 1, nt = f >> 7;
        const int n  = nt * 16 + (lane & 15);
        const int k0 = kh * 32 + ((lane >> 4) & 3) * 8;
        u16 tmp[8];
        #pragma unroll
        for (int j = 0; j < 8; ++j) {
          f16 hv = (f16)(src[(k0 + j) * HD + n] * sc);
          tmp[j] = *(u16*)&hv;
        }
        *(uint4*)(dst + f * 8) = *(const uint4*)tmp;
      }
    }
  } else if (w == NW) {
    const int t = threadIdx.x;
    const int mt = t >> 6, lane = t & 63;
    const int mm = lane & 15, qq = (lane >> 4) & 3;
    u16 tmp[8];
    #pragma unroll
    for (int j = 0; j < 8; ++j) {
      const int k = qq * 8 + j;
      f16 hv = (k < FIN) ? (f16)W_in[k * HD + mt * 16 + mm] : (f16)0.0f;
      tmp[j] = *(u16*)&hv;
    }
    *(uint4*)(wsW + NW * WFRAG + t * 8) = *(const uint4*)tmp;
  } else {
    static const int TIv[NTILES] = {0, 0, 1, 1, 1, 2, 2, 2, 3, 3};
    static const int TJv[NTILES] = {0, 1, 0, 1, 2, 1, 2, 3, 2, 3};
    u32* wsMsk = (u32*)(wsW + NW * WFRAG + WIN_U16);
    for (int idx = threadIdx.x; idx < MSK_U32; idx += 256) {
      const int tile = idx >> 7, rem = idx & 127;
      const int l = rem >> 1, pr = rem & 1;
      const int i  = TIv[tile] * 16 + (l & 15);
      const int j0 = TJv[tile] * 16 + ((l >> 4) & 3) * 4 + pr * 2;
      const u32 lo = (adj[i * NB + j0]     != 0) ? 0x3C00u : 0u;
      const u32 hi = (adj[i * NB + j0 + 1] != 0) ? 0x3C00u : 0u;
      wsMsk[idx] = lo | (hi << 16);
    }
  }
}

extern "C" __global__ void __launch_bounds__(NTH, 2)
gnn_fused(const float* __restrict__ x, const float* __restrict__ b_in,
          const u16* __restrict__ wsW, const float* __restrict__ bo,
          const float* __restrict__ ln_g, const float* __restrict__ ln_b,
          const float* __restrict__ Wp1, const float* __restrict__ bp1,
          const float* __restrict__ Wp2, const float* __restrict__ bp2,
          float* __restrict__ out) {
  __shared__ Smem s;
  const int tb = threadIdx.x;
  const int t  = tb & 63;                // lane within wave
  const int wv = tb >> 6;                // wave id
  const int m  = t & 15, q = t >> 4;
  const int g  = (int)blockIdx.x * NWAVE + wv;   // graph id (one per wave)

  const u16* wsWin = wsW + NW * WFRAG;
  u16* hw = s.hob[wv];                   // per-wave h/O round-trip buffer

  // per-lane mask fragments in REGISTERS (layer-invariant; compile-time
  // indices after unroll -> stays in VGPRs). 10 x uint2.
  uint2 mskr[NTILES];
  {
    const u32* wsMsk = (const u32*)(wsWin + WIN_U16);
    #pragma unroll
    for (int i = 0; i < NTILES; ++i)
      mskr[i] = *(const uint2*)(wsMsk + i * 128 + (t << 1));
  }

  // ---------------- input projection: h^T = W_in^T @ x^T (K=32 padded).
  // Nodes 0..31 -> hr registers; nodes 32..63 -> hrs (LDS residual home).
  f32x4 hr[2][4];   // hr[ng][mt]: h[node = ng*16+m][feat = mt*16 + q*4 + r]
  {
    #pragma unroll
    for (int ng = 0; ng < 4; ++ng) {
      U128h xb;
      xb.u = make_uint4(0u, 0u, 0u, 0u);
      const float* gx = x + (size_t)(g * NB + ng * 16 + m) * FIN;
      if (q == 0) {
        const float4 fa = *(const float4*)gx;
        const float4 fb = *(const float4*)(gx + 4);
        xb.u = make_uint4(packh2(fa.x, fa.y), packh2(fa.z, fa.w),
                          packh2(fb.x, fb.y), packh2(fb.z, fb.w));
      } else if (q == 1) {
        const float4 fc = *(const float4*)(gx + 8);
        xb.u.x = packh2(fc.x, fc.y);
        xb.u.y = packh2(fc.z, fc.w);
      }
      #pragma unroll
      for (int mt = 0; mt < 4; ++mt) {
        U128h aw;
        aw.u = *(const uint4*)(wsWin + (mt * 64 + t) * 8);
        f32x4 acc = {0.f, 0.f, 0.f, 0.f};
        acc = mfma32(aw.v8, xb.v8, acc);
        const f32x4 b4 = *(const f32x4*)&b_in[mt * 16 + q * 4];
        acc = acc + b4;
        if (ng < 2) hr[ng][mt] = acc;
        else        *(f32x4*)&s.hrs[wv][(ng - 2) * 4 + mt][t][0] = acc;
      }
    }
  }

  // ---------------- transformer layers: wave-autonomous, NO barriers.
  #pragma unroll 1
  for (int l = 0; l < NLAYERS; ++l) {
    const u16* wq  = wsW + (l * 4 + 0) * WFRAG;
    const u16* wk  = wsW + (l * 4 + 1) * WFRAG;
    const u16* wvd = wsW + (l * 4 + 2) * WFRAG;
    const u16* wo  = wsW + (l * 4 + 3) * WFRAG;
    const f32x4 z4 = {0.f, 0.f, 0.f, 0.f};

    // Issue V-weights (needed first) and Q-weights (needed 2 phases out).
    U128h aV[8], aQ[8];
    #pragma unroll
    for (int i = 0; i < 8; ++i) aV[i].u = *(const uint4*)(wvd + (i * 64 + t) * 8);
    #pragma unroll
    for (int i = 0; i < 8; ++i) aQ[i].u = *(const uint4*)(wq + (i * 64 + t) * 8);

    // packed h words: hp[ng][2*mt+c]; ng 0..1 from registers, 2..3 from hrs.
    u32 hp[4][8];
    #pragma unroll
    for (int ng = 0; ng < 2; ++ng)
      #pragma unroll
      for (int mt = 0; mt < 4; ++mt) {
        hp[ng][2 * mt]     = packh2(hr[ng][mt][0], hr[ng][mt][1]);
        hp[ng][2 * mt + 1] = packh2(hr[ng][mt][2], hr[ng][mt][3]);
      }
    #pragma unroll
    for (int ng = 2; ng < 4; ++ng)
      #pragma unroll
      for (int mt = 0; mt < 4; ++mt) {
        const f32x4 hv = *(const f32x4*)&s.hrs[wv][(ng - 2) * 4 + mt][t][0];
        hp[ng][2 * mt]     = packh2(hv[0], hv[1]);
        hp[ng][2 * mt + 1] = packh2(hv[2], hv[3]);
      }

    // write h to the round-trip buffer: [node][feat] f16, 16 x ds_write_b64
    #pragma unroll
    for (int ng = 0; ng < 4; ++ng)
      #pragma unroll
      for (int mt = 0; mt < 4; ++mt)
        *(uint2*)&hw[(ng * 16 + m) * HROW + mt * 16 + q * 4] =
            make_uint2(hp[ng][2 * mt], hp[ng][2 * mt + 1]);

    // V = H @ Wv (direct)  ->  vf[hh][kt] = V[kt*16+q*4+j][hh*16+m]
    // = exactly the V^T A-fragment PV needs: zero-shuffle V transpose.
    U64h vf[4][4];
    #pragma unroll
    for (int dt = 0; dt < 4; ++dt) {
      #pragma unroll
      for (int nt = 0; nt < 4; ++nt) {
        f32x4 acc = z4;
        acc = mfma16(pa4(hp[nt][0], hp[nt][1]), aV[dt * 2].v4h[0], acc);
        acc = mfma16(pa4(hp[nt][2], hp[nt][3]), aV[dt * 2].v4h[1], acc);
        acc = mfma16(pa4(hp[nt][4], hp[nt][5]), aV[dt * 2 + 1].v4h[0], acc);
        acc = mfma16(pa4(hp[nt][6], hp[nt][7]), aV[dt * 2 + 1].v4h[1], acc);
        vf[dt][nt].w[0] = packh2(acc[0], acc[1]);
        vf[dt][nt].w[1] = packh2(acc[2], acc[3]);
      }
    }
    // aV/hp dead. Issue K-weights; latency hides under the fused Q/K phase.
    U128h aK[8];
    #pragma unroll
    for (int i = 0; i < 8; ++i) aK[i].u = *(const uint4*)(wk + (i * 64 + t) * 8);

    // FUSED Q^T / K^T GEMMs: one b0/b1 read per ng feeds both.
    U64h qf[4][4], kf[4][4];
    #pragma unroll
    for (int ng = 0; ng < 4; ++ng) {
      U128h b0, b1;
      b0.u = *(const uint4*)&hw[(ng * 16 + m) * HROW + q * 8];
      b1.u = *(const uint4*)&hw[(ng * 16 + m) * HROW + 32 + q * 8];
      #pragma unroll
      for (int mt = 0; mt < 4; ++mt) {
        f32x4 accq = z4, acck = z4;
        accq = mfma32(aQ[mt * 2].v8,     b0.v8, accq);
        accq = mfma32(aQ[mt * 2 + 1].v8, b1.v8, accq);
        acck = mfma32(aK[mt * 2].v8,     b0.v8, acck);
        acck = mfma32(aK[mt * 2 + 1].v8, b1.v8, acck);
        qf[mt][ng].w[0] = packh2(accq[0], accq[1]);
        qf[mt][ng].w[1] = packh2(accq[2], accq[3]);
        kf[mt][ng].w[0] = packh2(acck[0], acck[1]);
        kf[mt][ng].w[1] = packh2(acck[2], acck[3]);
      }
    }

    // ---- band-tile attention, all 4 heads in-wave (no weight loads in
    // flight). S^T = K·Q^T ; P masked via REGISTER f16 0/1 frags; O^T = V^T·P^T.
    u32 opk[4][8];   // opk[ti][2*hh+c]: packed O, same form as hp
    {
      const h2 one2 = {(f16)1.0f, (f16)1.0f};
#define ATTN_HT(HH, TI, TJ0, NTJ, T0)                                          \
      {                                                                        \
        f32x4 ot = z4;                                                         \
        float dsum = 0.0f;                                                     \
        _Pragma("unroll")                                                      \
        for (int dt = 0; dt < (NTJ); ++dt) {                                   \
          const int tj = (TJ0) + dt;                                           \
          f32x4 st = mfma16(kf[HH][tj].v4, qf[HH][TI].v4, z4);                 \
          const uint2 mmv = mskr[(T0) + dt];                                   \
          U64h pp;                                                             \
          pp.w[0] = packh2(e2(st[0]), e2(st[1]));                              \
          pp.w[1] = packh2(e2(st[2]), e2(st[3]));                              \
          pp.h[0] *= *(const h2*)&mmv.x;                                       \
          pp.h[1] *= *(const h2*)&mmv.y;                                       \
          dsum = fdot2h(pp.h[0], one2, dsum);                                  \
          dsum = fdot2h(pp.h[1], one2, dsum);                                  \
          ot = mfma16(vf[HH][tj].v4, pp.v4, ot);                               \
        }                                                                      \
        dsum += __shfl_xor(dsum, 16, 64);                                      \
        dsum += __shfl_xor(dsum, 32, 64);                                      \
        const float rinv = 1.0f / dsum;                                        \
        opk[TI][2 * (HH)]     = packh2(ot[0] * rinv, ot[1] * rinv);            \
        opk[TI][2 * (HH) + 1] = packh2(ot[2] * rinv, ot[3] * rinv);            \
      }
      #pragma unroll
      for (int hh = 0; hh < 4; ++hh) {
        ATTN_HT(hh, 0, 0, 2, 0)
        ATTN_HT(hh, 1, 0, 3, 2)
        ATTN_HT(hh, 2, 1, 3, 5)
        ATTN_HT(hh, 3, 2, 2, 8)
      }
#undef ATTN_HT
    }

    // Issue Wo-weights now (latency covered by the O write-back).
    U128h aO[8];
    #pragma unroll
    for (int i = 0; i < 8; ++i) aO[i].u = *(const uint4*)(wo + (i * 64 + t) * 8);

    // write O over the h region (h fully consumed at the Q/K GEMM).
    #pragma unroll
    for (int ti = 0; ti < 4; ++ti)
      #pragma unroll
      for (int hh = 0; hh < 4; ++hh)
        *(uint2*)&hw[(ti * 16 + m) * HROW + hh * 16 + q * 4] =
            make_uint2(opk[ti][2 * hh], opk[ti][2 * hh + 1]);

    // u^T = Wo^T @ O^T + h + bo ; LN over feats (q-lane reduce).
    // Residual: ng 0..1 from hr registers; ng 2..3 from hrs (LDS), LN result
    // written back to hrs.
    {
      #pragma unroll
      for (int ng = 0; ng < 4; ++ng) {
        U128h ob0, ob1;
        ob0.u = *(const uint4*)&hw[(ng * 16 + m) * HROW + q * 8];
        ob1.u = *(const uint4*)&hw[(ng * 16 + m) * HROW + 32 + q * 8];
        f32x4 u4v[4];
        float s1 = 0.0f, s2 = 0.0f;
        #pragma unroll
        for (int mt = 0; mt < 4; ++mt) {
          f32x4 acc = z4;
          acc = mfma32(aO[mt * 2].v8,     ob0.v8, acc);
          acc = mfma32(aO[mt * 2 + 1].v8, ob1.v8, acc);
          const f32x4 bo4 = *(const f32x4*)&bo[l * HD + mt * 16 + q * 4];
          const f32x4 hres = (ng < 2)
              ? hr[ng][mt]
              : *(const f32x4*)&s.hrs[wv][(ng - 2) * 4 + mt][t][0];
          const f32x4 u4 = hres + acc + bo4;
          u4v[mt] = u4;
          #pragma unroll
          for (int r = 0; r < 4; ++r) { s1 += u4[r]; s2 += u4[r] * u4[r]; }
        }
        s1 += __shfl_xor(s1, 16, 64); s1 += __shfl_xor(s1, 32, 64);
        s2 += __shfl_xor(s2, 16, 64); s2 += __shfl_xor(s2, 32, 64);
        const float mu  = s1 * (1.0f / 64.0f);
        const float var = s2 * (1.0f / 64.0f) - mu * mu;
        const float rs  = rsqrtf(var + LN_EPS);
        #pragma unroll
        for (int mt = 0; mt < 4; ++mt) {
          const f32x4 g4  = *(const f32x4*)&ln_g[l * HD + mt * 16 + q * 4];
          const f32x4 be4 = *(const f32x4*)&ln_b[l * HD + mt * 16 + q * 4];
          f32x4 o4;
          #pragma unroll
          for (int r = 0; r < 4; ++r)
            o4[r] = (u4v[mt][r] - mu) * rs * g4[r] + be4[r];
          if (ng < 2) hr[ng][mt] = o4;
          else        *(f32x4*)&s.hrs[wv][(ng - 2) * 4 + mt][t][0] = o4;
        }
      }
    }
  }

  // ---------------- head: pool (in-lane ng-sum + m-lane butterfly), MLP via
  // per-wave 512 B scratch. All wave-internal: program order, no barriers.
  {
    #pragma unroll
    for (int mt = 0; mt < 4; ++mt) {
      const f32x4 h2v = *(const f32x4*)&s.hrs[wv][0 * 4 + mt][t][0];
      const f32x4 h3v = *(const f32x4*)&s.hrs[wv][1 * 4 + mt][t][0];
      f32x4 v = hr[0][mt] + hr[1][mt] + h2v + h3v;
      #pragma unroll
      for (int r = 0; r < 4; ++r) {
        float vv = v[r];
        vv += __shfl_xor(vv, 1, 64); vv += __shfl_xor(vv, 2, 64);
        vv += __shfl_xor(vv, 4, 64); vv += __shfl_xor(vv, 8, 64);
        v[r] = vv * (1.0f / 64.0f);
      }
      if (m == 0) *(f32x4*)&s.scr[wv][mt * 16 + q * 4] = v;
    }
  }
  {
    float acc = bp1[t];
    #pragma unroll 8
    for (int k = 0; k < HD; ++k) acc = fmaf(s.scr[wv][k], Wp1[k * HD + t], acc);
    s.scr[wv][64 + t] = fmaxf(acc, 0.0f);
  }
  {
    float a0 = bp2[t], a1 = bp2[t + 64];
    #pragma unroll 8
    for (int c = 0; c < HD; ++c) {
      const float yc = s.scr[wv][64 + c];
      a0 = fmaf(yc, Wp2[c * ODIM + t], a0);
      a1 = fmaf(yc, Wp2[c * ODIM + t + 64], a1);
    }
    out[g * ODIM + t]      = a0;
    out[g * ODIM + t + 64] = a1;
  }
}

extern "C" void kernel_launch(void* const* d_in, const int* in_sizes, int n_in,
                              void* d_out, int out_size, void* d_ws, size_t ws_size,
                              hipStream_t stream) {
  const float* x    = (const float*)d_in[0];
  const int*   adj  = (const int*)d_in[1];
  const float* W_in = (const float*)d_in[2];
  const float* b_in = (const float*)d_in[3];
  const float* Wq   = (const float*)d_in[4];
  const float* Wk   = (const float*)d_in[5];
  const float* Wv   = (const float*)d_in[6];
  const float* Wo   = (const float*)d_in[7];
  const float* bo   = (const float*)d_in[8];
  const float* lng  = (const float*)d_in[9];
  const float* lnb  = (const float*)d_in[10];
  const float* Wp1  = (const float*)d_in[11];
  const float* bp1  = (const float*)d_in[12];
  const float* Wp2  = (const float*)d_in[13];
  const float* bp2  = (const float*)d_in[14];
  float* outp = (float*)d_out;
  u16*   wsW  = (u16*)d_ws;

  hipLaunchKernelGGL(prep_pack, dim3(NW + 2), dim3(256), 0, stream,
                     Wq, Wk, Wv, Wo, W_in, adj, wsW);
  hipLaunchKernelGGL(gnn_fused, dim3(BTOT / NWAVE), dim3(NTH), 0, stream,
                     x, b_in, wsW, bo, lng, lnb, Wp1, bp1, Wp2, bp2, outp);
}

// Round 15
// 227.146 us; speedup vs baseline: 1.0433x; 1.0433x over previous
//
#include <hip/hip_runtime.h>
#include <stdint.h>

// Problem constants
#define NB       64
#define FIN      12
#define HD       64
#define NHEADS   4
#define DHEAD    16
#define NLAYERS  3
#define ODIM     128
#define LN_EPS   1e-5f
#define BTOT     8192

#define NTH      256   // 4 independent waves per block; ONE WAVE = ONE GRAPH
#define NWAVE    4
#define NW       (NLAYERS * 4)
#define WFRAG    4096  // u16 per packed weight
#define WIN_U16  2048  // packed W_in^T (zero-padded K=32)
#define NTILES   10    // band tiles (|tj-ti|<=1) of the 4x4 tile grid
#define MSK_U32  (NTILES * 64 * 2)   // 1280 u32 of f16 0/1 fragment masks
#define HROW     72    // u16 row stride of the per-wave h/O round-trip buffer

typedef unsigned int       u32;
typedef unsigned short     u16;
typedef unsigned long long u64;
typedef _Float16           f16;

typedef f16    f16x8 __attribute__((ext_vector_type(8)));
typedef f16    f16x4 __attribute__((ext_vector_type(4)));
typedef f16    h2    __attribute__((ext_vector_type(2)));
typedef __fp16 hh2   __attribute__((ext_vector_type(2)));
typedef float  f32x4 __attribute__((ext_vector_type(4)));
union U128h { uint4 u; f16x8 v8; f16x4 v4h[2]; h2 v2[4]; };
union U64h  { uint2 u; f16x4 v4; h2 h[2]; u32 w[2]; u16 s[4]; };

#if __has_builtin(__builtin_amdgcn_exp2f)
  __device__ __forceinline__ float e2(float x) { return __builtin_amdgcn_exp2f(x); }
#else
  __device__ __forceinline__ float e2(float x) { return exp2f(x); }
#endif

__device__ __forceinline__ float fdot2h(h2 a, h2 b, float c) {
#if __has_builtin(__builtin_amdgcn_fdot2)
  return __builtin_amdgcn_fdot2(a, b, c, false);
#else
  return c + (float)a[0] * (float)b[0] + (float)a[1] * (float)b[1];
#endif
}

#if __has_builtin(__builtin_amdgcn_cvt_pkrtz)
__device__ __forceinline__ u32 packh2(float a, float b) {
  hh2 p = __builtin_amdgcn_cvt_pkrtz(a, b);
  return *(u32*)&p;
}
#else
__device__ __forceinline__ u32 packh2(float a, float b) {
  h2 p = {(f16)a, (f16)b};
  return *(u32*)&p;
}
#endif

#if __has_builtin(__builtin_amdgcn_mfma_f32_16x16x16f16)
__device__ __forceinline__ f32x4 mfma16(f16x4 a, f16x4 b, f32x4 c) {
  return __builtin_amdgcn_mfma_f32_16x16x16f16(a, b, c, 0, 0, 0);
}
#elif __has_builtin(__builtin_amdgcn_mfma_f32_16x16x16_f16)
__device__ __forceinline__ f32x4 mfma16(f16x4 a, f16x4 b, f32x4 c) {
  return __builtin_amdgcn_mfma_f32_16x16x16_f16(a, b, c, 0, 0, 0);
}
#else
__device__ __forceinline__ f32x4 mfma16(f16x4 a, f16x4 b, f32x4 c) {
  f16x8 a8 = {a[0], a[1], a[2], a[3], (f16)0, (f16)0, (f16)0, (f16)0};
  f16x8 b8 = {b[0], b[1], b[2], b[3], (f16)0, (f16)0, (f16)0, (f16)0};
  return __builtin_amdgcn_mfma_f32_16x16x32_f16(a8, b8, c, 0, 0, 0);
}
#endif

__device__ __forceinline__ f32x4 mfma32(f16x8 a, f16x8 b, f32x4 c) {
  return __builtin_amdgcn_mfma_f32_16x16x32_f16(a, b, c, 0, 0, 0);
}

__device__ __forceinline__ f16x4 pa4(u32 w0, u32 w1) {
  U64h u; u.w[0] = w0; u.w[1] = w1; return u.v4;
}

// LDS: masks (block-shared, r11 scheme) + per-wave MLP scratch + per-wave h/O
// round-trip buffer. r15: masks BACK in LDS -- r13's masks-in-registers added
// 20 regs of whole-kernel liveness and pushed the allocator into ~5 MB of
// scratch spill (WRITE 9.3 MB vs 4.1 floor). Fused Q/K GEMM kept.
struct __align__(16) Smem {
  u32   Msk[MSK_U32];            // 5120 B
  float scr[NWAVE][128];         // 2048 B: pooled[64] + y1[64]
  u16   hob[NWAVE][64 * HROW];   // 36864 B: [wave][node][HROW] h then O
};  // 44032 B

// ---------------- prep: unchanged (verified 11 rounds).
extern "C" __global__ void __launch_bounds__(256)
prep_pack(const float* __restrict__ Wq, const float* __restrict__ Wk,
          const float* __restrict__ Wv, const float* __restrict__ Wo,
          const float* __restrict__ W_in, const int* __restrict__ adj,
          u16* __restrict__ wsW) {
  const int w = blockIdx.x;
  if (w < NW) {
    const int l = w >> 2, ty = w & 3;
    u16* dst = wsW + w * WFRAG;
    if (ty == 2) {
      const float* src = Wv + l * HD * HD;
      for (int f = threadIdx.x; f < 512; f += 256) {
        const int lane = f & 63, fi = f >> 6;
        const int dt = fi >> 1, c = fi & 1;
        const int mm = lane & 15, mq = (lane >> 4) & 3;
        u16 tmp[8];
        #pragma unroll
        for (int e = 0; e < 8; ++e) {
          const int kk = c * 2 + (e >> 2), j = e & 3;
          f16 hv = (f16)src[(kk * 16 + mq * 4 + j) * HD + dt * 16 + mm];
          tmp[e] = *(u16*)&hv;
        }
        *(uint4*)(dst + f * 8) = *(const uint4*)tmp;
      }
    } else {
      const float* src = (ty == 0 ? Wq : ty == 1 ? Wk : Wo) + l * HD * HD;
      const float sc = (ty == 0) ? (0.25f * 1.44269504f) : 1.0f;
      for (int f = threadIdx.x; f < 512; f += 256) {
        const int lane = f & 63, kh = (f >> 6) & 1, nt = f >> 7;
        const int n  = nt * 16 + (lane & 15);
        const int k0 = kh * 32 + ((lane >> 4) & 3) * 8;
        u16 tmp[8];
        #pragma unroll
        for (int j = 0; j < 8; ++j) {
          f16 hv = (f16)(src[(k0 + j) * HD + n] * sc);
          tmp[j] = *(u16*)&hv;
        }
        *(uint4*)(dst + f * 8) = *(const uint4*)tmp;
      }
    }
  } else if (w == NW) {
    const int t = threadIdx.x;
    const int mt = t >> 6, lane = t & 63;
    const int mm = lane & 15, qq = (lane >> 4) & 3;
    u16 tmp[8];
    #pragma unroll
    for (int j = 0; j < 8; ++j) {
      const int k = qq * 8 + j;
      f16 hv = (k < FIN) ? (f16)W_in[k * HD + mt * 16 + mm] : (f16)0.0f;
      tmp[j] = *(u16*)&hv;
    }
    *(uint4*)(wsW + NW * WFRAG + t * 8) = *(const uint4*)tmp;
  } else {
    static const int TIv[NTILES] = {0, 0, 1, 1, 1, 2, 2, 2, 3, 3};
    static const int TJv[NTILES] = {0, 1, 0, 1, 2, 1, 2, 3, 2, 3};
    u32* wsMsk = (u32*)(wsW + NW * WFRAG + WIN_U16);
    for (int idx = threadIdx.x; idx < MSK_U32; idx += 256) {
      const int tile = idx >> 7, rem = idx & 127;
      const int l = rem >> 1, pr = rem & 1;
      const int i  = TIv[tile] * 16 + (l & 15);
      const int j0 = TJv[tile] * 16 + ((l >> 4) & 3) * 4 + pr * 2;
      const u32 lo = (adj[i * NB + j0]     != 0) ? 0x3C00u : 0u;
      const u32 hi = (adj[i * NB + j0 + 1] != 0) ? 0x3C00u : 0u;
      wsMsk[idx] = lo | (hi << 16);
    }
  }
}

extern "C" __global__ void __launch_bounds__(NTH, 2)
gnn_fused(const float* __restrict__ x, const float* __restrict__ b_in,
          const u16* __restrict__ wsW, const float* __restrict__ bo,
          const float* __restrict__ ln_g, const float* __restrict__ ln_b,
          const float* __restrict__ Wp1, const float* __restrict__ bp1,
          const float* __restrict__ Wp2, const float* __restrict__ bp2,
          float* __restrict__ out) {
  __shared__ Smem s;
  const int tb = threadIdx.x;
  const int t  = tb & 63;                // lane within wave
  const int wv = tb >> 6;                // wave id
  const int m  = t & 15, q = t >> 4;
  const int g  = (int)blockIdx.x * NWAVE + wv;   // graph id (one per wave)

  const u16* wsWin = wsW + NW * WFRAG;
  u16* hw = s.hob[wv];                   // per-wave h/O round-trip buffer

  // stage masks into LDS (block-shared, layer-invariant); sole block barrier
  {
    const uint4* mg4 = (const uint4*)(wsWin + WIN_U16);
    if (tb < 256) ((uint4*)s.Msk)[tb] = mg4[tb];
    if (tb < 64)  ((uint4*)s.Msk)[256 + tb] = mg4[256 + tb];
  }
  __syncthreads();

  // ---------------- input projection: h^T = W_in^T @ x^T (K=32 padded),
  // x B-frags built straight from global (lane (m,q) supplies feats q*8+j).
  f32x4 hr[4][4];   // hr[ng][mt]: h[node = ng*16+m][feat = mt*16 + q*4 + r]
  {
    #pragma unroll
    for (int ng = 0; ng < 4; ++ng) {
      U128h xb;
      xb.u = make_uint4(0u, 0u, 0u, 0u);
      const float* gx = x + (size_t)(g * NB + ng * 16 + m) * FIN;
      if (q == 0) {
        const float4 fa = *(const float4*)gx;
        const float4 fb = *(const float4*)(gx + 4);
        xb.u = make_uint4(packh2(fa.x, fa.y), packh2(fa.z, fa.w),
                          packh2(fb.x, fb.y), packh2(fb.z, fb.w));
      } else if (q == 1) {
        const float4 fc = *(const float4*)(gx + 8);
        xb.u.x = packh2(fc.x, fc.y);
        xb.u.y = packh2(fc.z, fc.w);
      }
      #pragma unroll
      for (int mt = 0; mt < 4; ++mt) {
        U128h aw;
        aw.u = *(const uint4*)(wsWin + (mt * 64 + t) * 8);
        f32x4 acc = {0.f, 0.f, 0.f, 0.f};
        acc = mfma32(aw.v8, xb.v8, acc);
        const f32x4 b4 = *(const f32x4*)&b_in[mt * 16 + q * 4];
        hr[ng][mt] = acc + b4;
      }
    }
  }

  // ---------------- transformer layers: wave-autonomous, no further barriers.
  // B-fragments via the wave-private LDS round-trip (r11); Q and K GEMMs
  // FUSED (r13: one b0/b1 read pair feeds both).
  #pragma unroll 1
  for (int l = 0; l < NLAYERS; ++l) {
    const u16* wq  = wsW + (l * 4 + 0) * WFRAG;
    const u16* wk  = wsW + (l * 4 + 1) * WFRAG;
    const u16* wvd = wsW + (l * 4 + 2) * WFRAG;
    const u16* wo  = wsW + (l * 4 + 3) * WFRAG;
    const f32x4 z4 = {0.f, 0.f, 0.f, 0.f};

    // Issue V-weights (needed first) and Q-weights (needed 2 phases out).
    U128h aV[8], aQ[8];
    #pragma unroll
    for (int i = 0; i < 8; ++i) aV[i].u = *(const uint4*)(wvd + (i * 64 + t) * 8);
    #pragma unroll
    for (int i = 0; i < 8; ++i) aQ[i].u = *(const uint4*)(wq + (i * 64 + t) * 8);

    // packed h words: hp[ng][2*mt+c] = f16x2(hr[ng][mt][2c], [2c+1]).
    // Doubles as the V-GEMM A-fragment. (VALU work overlapping aV/aQ latency.)
    u32 hp[4][8];
    #pragma unroll
    for (int ng = 0; ng < 4; ++ng)
      #pragma unroll
      for (int mt = 0; mt < 4; ++mt) {
        hp[ng][2 * mt]     = packh2(hr[ng][mt][0], hr[ng][mt][1]);
        hp[ng][2 * mt + 1] = packh2(hr[ng][mt][2], hr[ng][mt][3]);
      }

    // write h to the round-trip buffer: [node][feat] f16, 16 x ds_write_b64
    #pragma unroll
    for (int ng = 0; ng < 4; ++ng)
      #pragma unroll
      for (int mt = 0; mt < 4; ++mt)
        *(uint2*)&hw[(ng * 16 + m) * HROW + mt * 16 + q * 4] =
            make_uint2(hp[ng][2 * mt], hp[ng][2 * mt + 1]);

    // V = H @ Wv (direct)  ->  vf[hh][kt] = V[kt*16+q*4+j][hh*16+m]
    // = exactly the V^T A-fragment PV needs: zero-shuffle V transpose.
    U64h vf[4][4];
    #pragma unroll
    for (int dt = 0; dt < 4; ++dt) {
      #pragma unroll
      for (int nt = 0; nt < 4; ++nt) {
        f32x4 acc = z4;
        acc = mfma16(pa4(hp[nt][0], hp[nt][1]), aV[dt * 2].v4h[0], acc);
        acc = mfma16(pa4(hp[nt][2], hp[nt][3]), aV[dt * 2].v4h[1], acc);
        acc = mfma16(pa4(hp[nt][4], hp[nt][5]), aV[dt * 2 + 1].v4h[0], acc);
        acc = mfma16(pa4(hp[nt][6], hp[nt][7]), aV[dt * 2 + 1].v4h[1], acc);
        vf[dt][nt].w[0] = packh2(acc[0], acc[1]);
        vf[dt][nt].w[1] = packh2(acc[2], acc[3]);
      }
    }
    // aV/hp dead. Issue K-weights; latency hides under the fused Q/K phase.
    U128h aK[8];
    #pragma unroll
    for (int i = 0; i < 8; ++i) aK[i].u = *(const uint4*)(wk + (i * 64 + t) * 8);

    // FUSED Q^T / K^T GEMMs: one b0/b1 read per ng feeds both.
    U64h qf[4][4], kf[4][4];
    #pragma unroll
    for (int ng = 0; ng < 4; ++ng) {
      U128h b0, b1;
      b0.u = *(const uint4*)&hw[(ng * 16 + m) * HROW + q * 8];
      b1.u = *(const uint4*)&hw[(ng * 16 + m) * HROW + 32 + q * 8];
      #pragma unroll
      for (int mt = 0; mt < 4; ++mt) {
        f32x4 accq = z4, acck = z4;
        accq = mfma32(aQ[mt * 2].v8,     b0.v8, accq);
        accq = mfma32(aQ[mt * 2 + 1].v8, b1.v8, accq);
        acck = mfma32(aK[mt * 2].v8,     b0.v8, acck);
        acck = mfma32(aK[mt * 2 + 1].v8, b1.v8, acck);
        qf[mt][ng].w[0] = packh2(accq[0], accq[1]);
        qf[mt][ng].w[1] = packh2(accq[2], accq[3]);
        kf[mt][ng].w[0] = packh2(acck[0], acck[1]);
        kf[mt][ng].w[1] = packh2(acck[2], acck[3]);
      }
    }

    // ---- band-tile attention, all 4 heads in-wave (no weight loads in
    // flight). S^T = K·Q^T ; P masked via LDS f16 0/1 frags; O^T = V^T·P^T.
    u32 opk[4][8];   // opk[ti][2*hh+c]: packed O, same form as hp
    {
      const h2 one2 = {(f16)1.0f, (f16)1.0f};
#define ATTN_HT(HH, TI, TJ0, NTJ, T0)                                          \
      {                                                                        \
        f32x4 ot = z4;                                                         \
        float dsum = 0.0f;                                                     \
        _Pragma("unroll")                                                      \
        for (int dt = 0; dt < (NTJ); ++dt) {                                   \
          const int tj = (TJ0) + dt;                                           \
          f32x4 st = mfma16(kf[HH][tj].v4, qf[HH][TI].v4, z4);                 \
          const uint2 mmv = *(const uint2*)&s.Msk[((T0) + dt) * 128 + (t << 1)]; \
          U64h pp;                                                             \
          pp.w[0] = packh2(e2(st[0]), e2(st[1]));                              \
          pp.w[1] = packh2(e2(st[2]), e2(st[3]));                              \
          pp.h[0] *= *(const h2*)&mmv.x;                                       \
          pp.h[1] *= *(const h2*)&mmv.y;                                       \
          dsum = fdot2h(pp.h[0], one2, dsum);                                  \
          dsum = fdot2h(pp.h[1], one2, dsum);                                  \
          ot = mfma16(vf[HH][tj].v4, pp.v4, ot);                               \
        }                                                                      \
        dsum += __shfl_xor(dsum, 16, 64);                                      \
        dsum += __shfl_xor(dsum, 32, 64);                                      \
        const float rinv = 1.0f / dsum;                                        \
        opk[TI][2 * (HH)]     = packh2(ot[0] * rinv, ot[1] * rinv);            \
        opk[TI][2 * (HH) + 1] = packh2(ot[2] * rinv, ot[3] * rinv);            \
      }
      #pragma unroll
      for (int hh = 0; hh < 4; ++hh) {
        ATTN_HT(hh, 0, 0, 2, 0)
        ATTN_HT(hh, 1, 0, 3, 2)
        ATTN_HT(hh, 2, 1, 3, 5)
        ATTN_HT(hh, 3, 2, 2, 8)
      }
#undef ATTN_HT
    }

    // Issue Wo-weights now (latency covered by the O write-back).
    U128h aO[8];
    #pragma unroll
    for (int i = 0; i < 8; ++i) aO[i].u = *(const uint4*)(wo + (i * 64 + t) * 8);

    // write O over the h region (h fully consumed at the Q/K GEMM).
    #pragma unroll
    for (int ti = 0; ti < 4; ++ti)
      #pragma unroll
      for (int hh = 0; hh < 4; ++hh)
        *(uint2*)&hw[(ti * 16 + m) * HROW + hh * 16 + q * 4] =
            make_uint2(opk[ti][2 * hh], opk[ti][2 * hh + 1]);

    // u^T = Wo^T @ O^T + h + bo ; LN over feats (q-lane reduce).
    {
      #pragma unroll
      for (int ng = 0; ng < 4; ++ng) {
        U128h ob0, ob1;
        ob0.u = *(const uint4*)&hw[(ng * 16 + m) * HROW + q * 8];
        ob1.u = *(const uint4*)&hw[(ng * 16 + m) * HROW + 32 + q * 8];
        float s1 = 0.0f, s2 = 0.0f;
        #pragma unroll
        for (int mt = 0; mt < 4; ++mt) {
          f32x4 acc = z4;
          acc = mfma32(aO[mt * 2].v8,     ob0.v8, acc);
          acc = mfma32(aO[mt * 2 + 1].v8, ob1.v8, acc);
          const f32x4 bo4 = *(const f32x4*)&bo[l * HD + mt * 16 + q * 4];
          const f32x4 u4 = hr[ng][mt] + acc + bo4;
          hr[ng][mt] = u4;
          #pragma unroll
          for (int r = 0; r < 4; ++r) { s1 += u4[r]; s2 += u4[r] * u4[r]; }
        }
        s1 += __shfl_xor(s1, 16, 64); s1 += __shfl_xor(s1, 32, 64);
        s2 += __shfl_xor(s2, 16, 64); s2 += __shfl_xor(s2, 32, 64);
        const float mu  = s1 * (1.0f / 64.0f);
        const float var = s2 * (1.0f / 64.0f) - mu * mu;
        const float rs  = rsqrtf(var + LN_EPS);
        #pragma unroll
        for (int mt = 0; mt < 4; ++mt) {
          const f32x4 g4  = *(const f32x4*)&ln_g[l * HD + mt * 16 + q * 4];
          const f32x4 be4 = *(const f32x4*)&ln_b[l * HD + mt * 16 + q * 4];
          #pragma unroll
          for (int r = 0; r < 4; ++r)
            hr[ng][mt][r] = (hr[ng][mt][r] - mu) * rs * g4[r] + be4[r];
        }
      }
    }
  }

  // ---------------- head: pool (in-lane ng-sum + m-lane butterfly), MLP via
  // per-wave 512 B scratch. All wave-internal: program order, no barriers.
  {
    #pragma unroll
    for (int mt = 0; mt < 4; ++mt) {
      f32x4 v = hr[0][mt] + hr[1][mt] + hr[2][mt] + hr[3][mt];
      #pragma unroll
      for (int r = 0; r < 4; ++r) {
        float vv = v[r];
        vv += __shfl_xor(vv, 1, 64); vv += __shfl_xor(vv, 2, 64);
        vv += __shfl_xor(vv, 4, 64); vv += __shfl_xor(vv, 8, 64);
        v[r] = vv * (1.0f / 64.0f);
      }
      if (m == 0) *(f32x4*)&s.scr[wv][mt * 16 + q * 4] = v;
    }
  }
  {
    float acc = bp1[t];
    #pragma unroll 8
    for (int k = 0; k < HD; ++k) acc = fmaf(s.scr[wv][k], Wp1[k * HD + t], acc);
    s.scr[wv][64 + t] = fmaxf(acc, 0.0f);
  }
  {
    float a0 = bp2[t], a1 = bp2[t + 64];
    #pragma unroll 8
    for (int c = 0; c < HD; ++c) {
      const float yc = s.scr[wv][64 + c];
      a0 = fmaf(yc, Wp2[c * ODIM + t], a0);
      a1 = fmaf(yc, Wp2[c * ODIM + t + 64], a1);
    }
    out[g * ODIM + t]      = a0;
    out[g * ODIM + t + 64] = a1;
  }
}

extern "C" void kernel_launch(void* const* d_in, const int* in_sizes, int n_in,
                              void* d_out, int out_size, void* d_ws, size_t ws_size,
                              hipStream_t stream) {
  const float* x    = (const float*)d_in[0];
  const int*   adj  = (const int*)d_in[1];
  const float* W_in = (const float*)d_in[2];
  const float* b_in = (const float*)d_in[3];
  const float* Wq   = (const float*)d_in[4];
  const float* Wk   = (const float*)d_in[5];
  const float* Wv   = (const float*)d_in[6];
  const float* Wo   = (const float*)d_in[7];
  const float* bo   = (const float*)d_in[8];
  const float* lng  = (const float*)d_in[9];
  const float* lnb  = (const float*)d_in[10];
  const float* Wp1  = (const float*)d_in[11];
  const float* bp1  = (const float*)d_in[12];
  const float* Wp2  = (const float*)d_in[13];
  const float* bp2  = (const float*)d_in[14];
  float* outp = (float*)d_out;
  u16*   wsW  = (u16*)d_ws;

  hipLaunchKernelGGL(prep_pack, dim3(NW + 2), dim3(256), 0, stream,
                     Wq, Wk, Wv, Wo, W_in, adj, wsW);
  hipLaunchKernelGGL(gnn_fused, dim3(BTOT / NWAVE), dim3(NTH), 0, stream,
                     x, b_in, wsW, bo, lng, lnb, Wp1, bp1, Wp2, bp2, outp);
}